// Round 7
// baseline (72.280 us; speedup 1.0000x reference)
//
#include <hip/hip_runtime.h>

namespace {

constexpr int R      = 4;             // radius = int(4*1 + 0.5)
constexpr int TSX    = 64;            // output tile width
constexpr int TSY    = 64;            // output tile height
constexpr int HROWS  = TSY + 2 * R;   // 72 h-pass rows (incl. vertical halo)
constexpr int HSTR   = 68;            // s_h row stride (floats) — proven low-conflict
constexpr int IMG_H  = 512;
constexpr int IMG_W  = 512;
constexpr int NITEMS = HROWS * 16;    // 1152 h-pass items (16 float4 per row)
constexpr int NB_X   = IMG_W / TSX;   // 8 block columns

__device__ __forceinline__ int clampi(int v, int lo, int hi) {
    return v < lo ? lo : (v > hi ? hi : v);
}

__global__ __launch_bounds__(256)
void gauss_blur_kernel(const float* __restrict__ in, float* __restrict__ out) {
    const float KW[9] = {
        1.3383062e-4f, 4.4318616e-3f, 5.3990966e-2f, 2.4197144e-1f,
        3.9894347e-1f, 2.4197144e-1f, 5.3990966e-2f, 4.4318616e-3f,
        1.3383062e-4f};

    __shared__ float s_h[HROWS * HSTR];   // 72 x 64 h-pass result (19584 B) — ONLY LDS buffer

    const int tid = threadIdx.x;
    const int b   = blockIdx.z;
    const int ty0 = blockIdx.y * TSY;
    const int tx0 = blockIdx.x * TSX;

    const float* __restrict__ inb = in + (size_t)b * IMG_H * IMG_W;

    const int  j    = tid & 15;           // float4 column within row (item space)
    const bool isL  = (j == 0);
    const bool isR  = (j == 15);
    const bool blkL = (blockIdx.x == 0);
    const bool blkR = (blockIdx.x == NB_X - 1);

    // ---- phase 1a: issue all global loads (independent, batched for MLP) ----
    // Item i = tid + 256k -> h-row r = i>>4, f4-col j = i&15. Each thread loads
    // ONE aligned float4 (its own window center); lanes j==0/15 additionally
    // load the row-edge halo float4 (or splat the clamped edge for edge blocks).
    float4 v[5], hx[5];
    #pragma unroll
    for (int k = 0; k < 5; ++k) {
        const int i = tid + 256 * k;
        if (i < NITEMS) {                 // wave-uniform (whole waves drop out)
            const int r  = i >> 4;
            const int gy = clampi(ty0 - R + r, 0, IMG_H - 1);
            const float* rp = inb + (size_t)gy * IMG_W;
            v[k] = *reinterpret_cast<const float4*>(rp + tx0 + 4 * j);
            if (isL) {
                if (blkL) { float e = rp[0]; hx[k] = make_float4(e, e, e, e); }
                else      { hx[k] = *reinterpret_cast<const float4*>(rp + tx0 - 4); }
            }
            if (isR) {
                if (blkR) { float e = rp[IMG_W - 1]; hx[k] = make_float4(e, e, e, e); }
                else      { hx[k] = *reinterpret_cast<const float4*>(rp + tx0 + TSX); }
            }
        }
    }

    // ---- phase 1b: neighbor exchange via shuffles + horizontal 9-tap -> LDS ----
    #pragma unroll
    for (int k = 0; k < 5; ++k) {
        const int i = tid + 256 * k;
        if (i < NITEMS) {                 // wave-uniform -> full-wave shuffles
            float4 lf, rt;
            lf.x = __shfl_up(v[k].x, 1);  lf.y = __shfl_up(v[k].y, 1);
            lf.z = __shfl_up(v[k].z, 1);  lf.w = __shfl_up(v[k].w, 1);
            rt.x = __shfl_down(v[k].x, 1); rt.y = __shfl_down(v[k].y, 1);
            rt.z = __shfl_down(v[k].z, 1); rt.w = __shfl_down(v[k].w, 1);
            if (isL) lf = hx[k];          // row boundary: shuffle crossed rows
            if (isR) rt = hx[k];

            const float w[12] = {lf.x, lf.y, lf.z, lf.w,
                                 v[k].x, v[k].y, v[k].z, v[k].w,
                                 rt.x, rt.y, rt.z, rt.w};
            float a0 = 0.f, a1 = 0.f, a2 = 0.f, a3 = 0.f;
            #pragma unroll
            for (int t = 0; t < 9; ++t) {
                a0 = fmaf(KW[t], w[t + 0], a0);
                a1 = fmaf(KW[t], w[t + 1], a1);
                a2 = fmaf(KW[t], w[t + 2], a2);
                a3 = fmaf(KW[t], w[t + 3], a3);
            }
            const int r = i >> 4;
            float4 o = {a0, a1, a2, a3};
            *reinterpret_cast<float4*>(&s_h[r * HSTR + 4 * j]) = o;
        }
    }
    __syncthreads();

    // ---- phase 2: vertical 9-tap in registers, 4-wide x 4-tall patches ----
    const int px  = tid & 15;
    const int py  = tid >> 4;
    const int lx  = 4 * px;

    float4 acc[4] = {{0,0,0,0},{0,0,0,0},{0,0,0,0},{0,0,0,0}};
    #pragma unroll
    for (int t = 0; t < 12; ++t) {
        float4 h = *reinterpret_cast<const float4*>(&s_h[(4 * py + t) * HSTR + lx]);
        #pragma unroll
        for (int rr = 0; rr < 4; ++rr) {
            const int kk = t - rr;
            if (kk >= 0 && kk < 9) {
                acc[rr].x = fmaf(KW[kk], h.x, acc[rr].x);
                acc[rr].y = fmaf(KW[kk], h.y, acc[rr].y);
                acc[rr].z = fmaf(KW[kk], h.z, acc[rr].z);
                acc[rr].w = fmaf(KW[kk], h.w, acc[rr].w);
            }
        }
    }

    float* __restrict__ outb = out + (size_t)b * IMG_H * IMG_W;
    #pragma unroll
    for (int rr = 0; rr < 4; ++rr) {
        *reinterpret_cast<float4*>(
            &outb[(size_t)(ty0 + 4 * py + rr) * IMG_W + tx0 + lx]) = acc[rr];
    }
}

}  // namespace

extern "C" void kernel_launch(void* const* d_in, const int* in_sizes, int n_in,
                              void* d_out, int out_size, void* d_ws, size_t ws_size,
                              hipStream_t stream) {
    const float* x = (const float*)d_in[0];
    float* out = (float*)d_out;

    const int batch = in_sizes[0] / (IMG_H * IMG_W);  // 128

    dim3 grid(IMG_W / TSX, IMG_H / TSY, batch);       // (8, 8, 128)
    gauss_blur_kernel<<<grid, 256, 0, stream>>>(x, out);
}